// Round 14
// baseline (475.707 us; speedup 1.0000x reference)
//
#include <hip/hip_runtime.h>
#include <hip/hip_bf16.h>
#include <hip/hip_cooperative_groups.h>

namespace cg = cooperative_groups;

constexpr int B_ = 4, N_ = 2048, NFEAT = 512, NHID = 64, NHEADS = 4, NCLASS = 64;
constexpr int MAXDEG = 128;
#define LRELU_ALPHA 0.2f

typedef __attribute__((ext_vector_type(8))) short short8;
typedef __attribute__((ext_vector_type(4))) float f32x4;

__device__ __forceinline__ unsigned short f2bf_rne(float f) {
  unsigned int u = __float_as_uint(f);
  unsigned int r = (u + 0x7FFFu + ((u >> 16) & 1u)) >> 16;
  return (unsigned short)r;
}
__device__ __forceinline__ float bf2f(unsigned short h) {
  return __uint_as_float(((unsigned int)h) << 16);
}
__device__ __forceinline__ float ldval(const float* p) { return *p; }
__device__ __forceinline__ float ldval(const unsigned short* p) { return bf2f(*p); }

// ---------------------------------------------------------------------------
// Sparse attention aggregation: 16-deep then 8-deep software pipeline.
// ---------------------------------------------------------------------------
template <int RS, typename T>
__device__ __forceinline__ float sparse_agg(
    const T* __restrict__ plane, const float* __restrict__ sdb,
    const int* __restrict__ nb, int dg, float ss, int lane) {
  float acc0 = 0.f, acc1 = 0.f, acc2 = 0.f, acc3 = 0.f;
  float den0 = 0.f, den1 = 0.f, den2 = 0.f, den3 = 0.f;
  int k = 0;
  for (; k + 16 <= dg; k += 16) {
    int m[16];
    float sv[16], hv[16];
#pragma unroll
    for (int j = 0; j < 16; ++j) m[j] = nb[k + j];
#pragma unroll
    for (int j = 0; j < 16; ++j) sv[j] = sdb[m[j]];
#pragma unroll
    for (int j = 0; j < 16; ++j) hv[j] = ldval(&plane[(size_t)m[j] * RS + lane]);
#pragma unroll
    for (int j = 0; j < 16; ++j) {
      float s = ss + sv[j];
      float lr = s > 0.f ? s : LRELU_ALPHA * s;
      float ev = __expf(-lr);
      switch (j & 3) {
        case 0: den0 += ev; acc0 = fmaf(ev, hv[j], acc0); break;
        case 1: den1 += ev; acc1 = fmaf(ev, hv[j], acc1); break;
        case 2: den2 += ev; acc2 = fmaf(ev, hv[j], acc2); break;
        default: den3 += ev; acc3 = fmaf(ev, hv[j], acc3); break;
      }
    }
  }
  for (; k + 8 <= dg; k += 8) {
    int m[8];
    float sv[8], hv[8];
#pragma unroll
    for (int j = 0; j < 8; ++j) m[j] = nb[k + j];
#pragma unroll
    for (int j = 0; j < 8; ++j) sv[j] = sdb[m[j]];
#pragma unroll
    for (int j = 0; j < 8; ++j) hv[j] = ldval(&plane[(size_t)m[j] * RS + lane]);
#pragma unroll
    for (int j = 0; j < 8; ++j) {
      float s = ss + sv[j];
      float lr = s > 0.f ? s : LRELU_ALPHA * s;
      float ev = __expf(-lr);
      if (j & 1) { den1 += ev; acc1 = fmaf(ev, hv[j], acc1); }
      else       { den0 += ev; acc0 = fmaf(ev, hv[j], acc0); }
    }
  }
  for (; k < dg; ++k) {
    int m = nb[k];
    float s = ss + sdb[m];
    float lr = s > 0.f ? s : LRELU_ALPHA * s;
    float ev = __expf(-lr);
    den0 += ev;
    acc0 = fmaf(ev, ldval(&plane[(size_t)m * RS + lane]), acc0);
  }
  return ((acc0 + acc1) + (acc2 + acc3)) / ((den0 + den1) + (den2 + den3));
}

// ---------------------------------------------------------------------------
// One 64x64 split-bf16 MFMA GEMM tile + fused rowdot epilogue, on shared smem.
// MODE 0: X fp32 (split in staging), Yh bf16 [b,n,head*64+d], rowdot a1[head].
// MODE 1: X pre-split hi/lo ushort, Yf fp32 [row,64], rowdot a2.
// ---------------------------------------------------------------------------
template <int K, int MODE>
__device__ __forceinline__ void gemm_tile(
    int wi, const float* __restrict__ Xf, const unsigned short* __restrict__ Xh,
    const unsigned short* __restrict__ Xl, const unsigned short* __restrict__ Wth,
    const unsigned short* __restrict__ Wtl, const float* __restrict__ avec,
    unsigned short* __restrict__ Yh, float* __restrict__ Yf,
    float* __restrict__ so_src, float* __restrict__ so_dst,
    unsigned char* smem) {
  auto xsh = (unsigned short(*)[72])(smem);
  auto xsl = (unsigned short(*)[72])(smem + 9216);
  auto wsh = (unsigned short(*)[72])(smem + 18432);
  auto wsl = (unsigned short(*)[72])(smem + 27648);
  int tid = threadIdx.x;
  int w = tid >> 6, l = tid & 63;
  int row0, head;
  if (MODE == 0) {
    int xcd = wi & 7, hh = (wi >> 3) & 3, q = wi >> 5;
    row0 = (q * 8 + xcd) * 64;
    head = hh;
  } else {
    row0 = wi * 64;
    head = 0;
  }
  const unsigned short* wh = Wth + (size_t)head * 64 * K;
  const unsigned short* wl = Wtl + (size_t)head * 64 * K;
  const float* av = avec + head * 128;

  int sr = tid >> 2;
  int sc = (tid & 3) * 16;

  f32x4 acc[4];
#pragma unroll
  for (int nt = 0; nt < 4; ++nt) acc[nt] = (f32x4){0.f, 0.f, 0.f, 0.f};

  for (int k0 = 0; k0 < K; k0 += 64) {
    if (MODE == 0) {
      const float* s0 = Xf + (size_t)(row0 + sr) * K + k0 + sc;
      float4 f0 = ((const float4*)s0)[0];
      float4 f1 = ((const float4*)s0)[1];
      float4 f2 = ((const float4*)s0)[2];
      float4 f3 = ((const float4*)s0)[3];
      float v[16] = {f0.x, f0.y, f0.z, f0.w, f1.x, f1.y, f1.z, f1.w,
                     f2.x, f2.y, f2.z, f2.w, f3.x, f3.y, f3.z, f3.w};
      short8 hi0, hi1, lo0, lo1;
#pragma unroll
      for (int j = 0; j < 8; ++j) {
        unsigned short hh = f2bf_rne(v[j]);
        hi0[j] = (short)hh;
        lo0[j] = (short)f2bf_rne(v[j] - bf2f(hh));
        unsigned short hh1 = f2bf_rne(v[8 + j]);
        hi1[j] = (short)hh1;
        lo1[j] = (short)f2bf_rne(v[8 + j] - bf2f(hh1));
      }
      *(short8*)&xsh[sr][sc]     = hi0;
      *(short8*)&xsh[sr][sc + 8] = hi1;
      *(short8*)&xsl[sr][sc]     = lo0;
      *(short8*)&xsl[sr][sc + 8] = lo1;
    } else {
      const unsigned short* s0 = Xh + (size_t)(row0 + sr) * K + k0 + sc;
      const unsigned short* s1 = Xl + (size_t)(row0 + sr) * K + k0 + sc;
      *(short8*)&xsh[sr][sc]     = *(const short8*)s0;
      *(short8*)&xsh[sr][sc + 8] = *(const short8*)(s0 + 8);
      *(short8*)&xsl[sr][sc]     = *(const short8*)s1;
      *(short8*)&xsl[sr][sc + 8] = *(const short8*)(s1 + 8);
    }
    {
      const unsigned short* s2 = wh + (size_t)sr * K + k0 + sc;
      const unsigned short* s3 = wl + (size_t)sr * K + k0 + sc;
      *(short8*)&wsh[sr][sc]     = *(const short8*)s2;
      *(short8*)&wsh[sr][sc + 8] = *(const short8*)(s2 + 8);
      *(short8*)&wsl[sr][sc]     = *(const short8*)s3;
      *(short8*)&wsl[sr][sc + 8] = *(const short8*)(s3 + 8);
    }
    __syncthreads();
#pragma unroll
    for (int ks = 0; ks < 2; ++ks) {
      int ko = ks * 32 + (l >> 4) * 8;
      int ar = 16 * w + (l & 15);
      short8 ah = *(const short8*)&xsh[ar][ko];
      short8 al = *(const short8*)&xsl[ar][ko];
#pragma unroll
      for (int nt = 0; nt < 4; ++nt) {
        int br = 16 * nt + (l & 15);
        short8 bh = *(const short8*)&wsh[br][ko];
        short8 bl = *(const short8*)&wsl[br][ko];
        acc[nt] = __builtin_amdgcn_mfma_f32_16x16x32_bf16(ah, bh, acc[nt], 0, 0, 0);
        acc[nt] = __builtin_amdgcn_mfma_f32_16x16x32_bf16(ah, bl, acc[nt], 0, 0, 0);
        acc[nt] = __builtin_amdgcn_mfma_f32_16x16x32_bf16(al, bh, acc[nt], 0, 0, 0);
      }
    }
    __syncthreads();
  }

  int col = (l & 15);
#pragma unroll
  for (int nt = 0; nt < 4; ++nt) {
#pragma unroll
    for (int j = 0; j < 4; ++j) {
      int r = 16 * w + (l >> 4) * 4 + j;
      size_t gr = row0 + r;
      if (MODE == 0)
        Yh[gr * (NHEADS * 64) + head * 64 + 16 * nt + col] = f2bf_rne(acc[nt][j]);
      else
        Yf[gr * 64 + 16 * nt + col] = acc[nt][j];
    }
  }
  float aS[4], aD[4];
#pragma unroll
  for (int nt = 0; nt < 4; ++nt) {
    aS[nt] = av[16 * nt + col];
    aD[nt] = av[64 + 16 * nt + col];
  }
  float s1[4] = {0.f, 0.f, 0.f, 0.f}, s2[4] = {0.f, 0.f, 0.f, 0.f};
#pragma unroll
  for (int nt = 0; nt < 4; ++nt)
#pragma unroll
    for (int j = 0; j < 4; ++j) {
      s1[j] = fmaf(acc[nt][j], aS[nt], s1[j]);
      s2[j] = fmaf(acc[nt][j], aD[nt], s2[j]);
    }
#pragma unroll
  for (int off = 1; off < 16; off <<= 1) {
#pragma unroll
    for (int j = 0; j < 4; ++j) {
      s1[j] += __shfl_xor(s1[j], off);
      s2[j] += __shfl_xor(s2[j], off);
    }
  }
  if (col == 0) {
#pragma unroll
    for (int j = 0; j < 4; ++j) {
      int r = 16 * w + (l >> 4) * 4 + j;
      int gr = row0 + r;
      size_t si;
      if (MODE == 0) {
        int b = gr >> 11, n = gr & (N_ - 1);
        si = (size_t)(b * NHEADS + head) * N_ + n;
      } else {
        si = gr;
      }
      so_src[si] = s1[j];
      so_dst[si] = s2[j];
    }
  }
}

// ---------------------------------------------------------------------------
// Mega cooperative kernel: prep -> gemm1 -> attn1 -> gemm2 -> attn2 with
// grid.sync() between phases. All phases grid-stride -> any grid size works.
// ---------------------------------------------------------------------------
__global__ __launch_bounds__(256) void spgat_mega(
    const float* __restrict__ x, const float* __restrict__ adj,
    const float* __restrict__ W1, const float* __restrict__ a1,
    const float* __restrict__ W2, const float* __restrict__ a2,
    float* __restrict__ out, unsigned short* __restrict__ h,
    float* __restrict__ g, float* __restrict__ ssrc, float* __restrict__ sdst,
    float* __restrict__ tsrc, float* __restrict__ tdst,
    int* __restrict__ nbr, int* __restrict__ deg,
    unsigned short* __restrict__ wt1h, unsigned short* __restrict__ wt1l,
    unsigned short* __restrict__ wt2h, unsigned short* __restrict__ wt2l,
    unsigned short* __restrict__ h1h, unsigned short* __restrict__ h1l) {
  __shared__ alignas(16) unsigned char smem[36864];
  __shared__ int cnt;
  cg::grid_group grid = cg::this_grid();
  int tid = threadIdx.x;

  // ---- Phase 0: prep (adj list build + W1/W2 transpose-split) ----
  for (int item = blockIdx.x; item < N_ + 36; item += gridDim.x) {
    if (item < N_) {
      int n = item;
      if (tid == 0) cnt = 0;
      __syncthreads();
      for (int m = tid; m < N_; m += 256) {
        bool nz = adj[(size_t)n * N_ + m] != 0.0f;
        unsigned long long mask = __ballot(nz);
        int lane = tid & 63;
        int num = __popcll(mask);
        if (num) {               // wave-uniform
          int base = 0;
          if (lane == 0) base = atomicAdd(&cnt, num);
          base = __shfl(base, 0);
          if (nz) {
            int pos = base + __popcll(mask & ((1ull << lane) - 1ull));
            if (pos < MAXDEG) nbr[n * MAXDEG + pos] = m;
          }
        }
      }
      __syncthreads();
      if (tid == 0) deg[n] = cnt < MAXDEG ? cnt : MAXDEG;
      __syncthreads();                 // cnt reuse guard across loop iterations
    } else {
      auto ts = (float(*)[65])smem;     // 64*65*4 = 16640 B
      int wk = item - N_;
      const float* W;
      unsigned short *wth, *wtl;
      int KK, hh, k0;
      if (wk < 32) { W = W1; wth = wt1h; wtl = wt1l; KK = 512; hh = wk >> 3; k0 = (wk & 7) * 64; }
      else { wk -= 32; W = W2; wth = wt2h; wtl = wt2l; KK = 256; hh = 0; k0 = wk * 64; }
      int kr = tid >> 2, nc = (tid & 3) * 16;
      const float* src = W + ((size_t)hh * KK + k0 + kr) * 64 + nc;
#pragma unroll
      for (int j = 0; j < 4; ++j)
        *(float4*)&ts[kr][nc + 4 * j] = *(const float4*)(src + 4 * j);
      __syncthreads();
      int n = tid >> 2, kc = (tid & 3) * 16;
      short8 h0, h1v, l0, l1v;
#pragma unroll
      for (int j = 0; j < 8; ++j) {
        float a = ts[kc + j][n];
        float b = ts[kc + 8 + j][n];
        unsigned short ah = f2bf_rne(a), bh = f2bf_rne(b);
        h0[j] = (short)ah; h1v[j] = (short)bh;
        l0[j] = (short)f2bf_rne(a - bf2f(ah));
        l1v[j] = (short)f2bf_rne(b - bf2f(bh));
      }
      size_t o = ((size_t)hh * 64 + n) * KK + k0 + kc;
      *(short8*)&wth[o]     = h0;
      *(short8*)&wth[o + 8] = h1v;
      *(short8*)&wtl[o]     = l0;
      *(short8*)&wtl[o + 8] = l1v;
      __syncthreads();                 // ts reuse guard across loop iterations
    }
  }
  __threadfence();
  grid.sync();

  // ---- Phase 1: gemm1 (512 tiles) ----
  for (int wi = blockIdx.x; wi < B_ * N_ / 64 * NHEADS; wi += gridDim.x)
    gemm_tile<NFEAT, 0>(wi, x, nullptr, nullptr, wt1h, wt1l, a1, h, nullptr,
                        ssrc, sdst, smem);
  __threadfence();
  grid.sync();

  // ---- Phase 2: attn1 (8192 items; block = 4 waves = 4 heads) ----
  for (int bn = blockIdx.x; bn < B_ * N_; bn += gridDim.x) {
    int n = bn & (N_ - 1), b = bn >> 11;
    int w = tid >> 6, lane = tid & 63;
    int* lds_nbr = (int*)smem;
    int dg = deg[n];
    for (int k = tid; k < dg; k += 256) lds_nbr[k] = nbr[n * MAXDEG + k];
    __syncthreads();
    int bh = b * NHEADS + w;
    float ss = ssrc[(size_t)bh * N_ + n];
    const float* sdb = sdst + (size_t)bh * N_;
    const unsigned short* plane = h + (size_t)b * N_ * (NHEADS * 64) + w * 64;
    float o = sparse_agg<NHEADS * 64>(plane, sdb, lds_nbr, dg, ss, lane);
    o = o > 0.f ? o : expm1f(o);
    unsigned short hi = f2bf_rne(o);
    size_t oi = (size_t)bn * (NHEADS * NHID) + w * 64 + lane;
    h1h[oi] = hi;
    h1l[oi] = f2bf_rne(o - bf2f(hi));
    __syncthreads();                   // lds_nbr reuse guard
  }
  __threadfence();
  grid.sync();

  // ---- Phase 3: gemm2 (128 tiles) ----
  for (int wi = blockIdx.x; wi < B_ * N_ / 64; wi += gridDim.x)
    gemm_tile<256, 1>(wi, nullptr, h1h, h1l, wt2h, wt2l, a2, nullptr, g,
                      tsrc, tdst, smem);
  __threadfence();
  grid.sync();

  // ---- Phase 4: attn2 (2048 wave-items = 512 block-items) ----
  for (int it = blockIdx.x; it < B_ * N_ / 4; it += gridDim.x) {
    int w = tid >> 6, lane = tid & 63;
    int gr = it * 4 + w;
    int n = gr & (N_ - 1);
    int b = gr >> 11;
    float o = sparse_agg<64>(g + (size_t)b * N_ * 64, tdst + (size_t)b * N_,
                             nbr + n * MAXDEG, deg[n], tsrc[gr], lane);
    out[(size_t)gr * 64 + lane] = o > 0.f ? o : expm1f(o);
  }
}

// ---------------------------------------------------------------------------
extern "C" void kernel_launch(void* const* d_in, const int* in_sizes, int n_in,
                              void* d_out, int out_size, void* d_ws, size_t ws_size,
                              hipStream_t stream) {
  const float* x   = (const float*)d_in[0];   // [B,N,512]
  const float* adj = (const float*)d_in[1];   // [N,N]
  const float* W1  = (const float*)d_in[2];   // [H,512,64]
  const float* a1  = (const float*)d_in[3];   // [H,128]
  const float* W2  = (const float*)d_in[4];   // [256,64]
  const float* a2  = (const float*)d_in[5];   // [128]
  float* out = (float*)d_out;                 // [B,N,64] fp32

  char* ws = (char*)d_ws;
  unsigned short* h = (unsigned short*)ws; ws += (size_t)B_ * N_ * 256 * 2;  // 4.2 MB bf16
  float* g    = (float*)ws; ws += (size_t)B_ * N_ * 64 * 4;           // 2 MB
  float* ssrc = (float*)ws; ws += (size_t)B_ * NHEADS * N_ * 4;
  float* sdst = (float*)ws; ws += (size_t)B_ * NHEADS * N_ * 4;
  float* tsrc = (float*)ws; ws += (size_t)B_ * N_ * 4;
  float* tdst = (float*)ws; ws += (size_t)B_ * N_ * 4;
  int*   nbr  = (int*)ws;   ws += (size_t)N_ * MAXDEG * 4;            // 1 MB
  int*   deg  = (int*)ws;   ws += (size_t)N_ * 4;
  ws = (char*)(((size_t)ws + 255) & ~(size_t)255);
  unsigned short* wt1h = (unsigned short*)ws; ws += (size_t)NHEADS * 64 * NFEAT * 2;
  unsigned short* wt1l = (unsigned short*)ws; ws += (size_t)NHEADS * 64 * NFEAT * 2;
  unsigned short* wt2h = (unsigned short*)ws; ws += (size_t)64 * 256 * 2;
  unsigned short* wt2l = (unsigned short*)ws; ws += (size_t)64 * 256 * 2;
  unsigned short* h1h  = (unsigned short*)ws; ws += (size_t)B_ * N_ * 256 * 2;   // 4.2 MB
  unsigned short* h1l  = (unsigned short*)ws; ws += (size_t)B_ * N_ * 256 * 2;   // 4.2 MB

  // Cooperative grid sized to guaranteed co-residency (grid-stride phases
  // tolerate any size; 512 = full coverage for gemm1/attn2 at 1 item/block).
  int occ = 0;
  hipOccupancyMaxActiveBlocksPerMultiprocessor(&occ, (const void*)spgat_mega, 256, 0);
  if (occ < 1) occ = 1;
  int gridn = occ * 256;                 // 256 CUs on MI355X
  if (gridn > 512) gridn = 512;

  void* args[] = {(void*)&x,   (void*)&adj, (void*)&W1,  (void*)&a1,
                  (void*)&W2,  (void*)&a2,  (void*)&out, (void*)&h,
                  (void*)&g,   (void*)&ssrc,(void*)&sdst,(void*)&tsrc,
                  (void*)&tdst,(void*)&nbr, (void*)&deg, (void*)&wt1h,
                  (void*)&wt1l,(void*)&wt2h,(void*)&wt2l,(void*)&h1h,
                  (void*)&h1l};
  hipLaunchCooperativeKernel((const void*)spgat_mega, dim3(gridn), dim3(256),
                             args, 0, stream);
}

// Round 15
// 143.559 us; speedup vs baseline: 3.3137x; 3.3137x over previous
//
#include <hip/hip_runtime.h>
#include <hip/hip_bf16.h>

constexpr int B_ = 4, N_ = 2048, NFEAT = 512, NHID = 64, NHEADS = 4, NCLASS = 64;
constexpr int MAXDEG = 128;
#define LRELU_ALPHA 0.2f

typedef __attribute__((ext_vector_type(8))) short short8;
typedef __attribute__((ext_vector_type(4))) float f32x4;

__device__ __forceinline__ unsigned short f2bf_rne(float f) {
  unsigned int u = __float_as_uint(f);
  unsigned int r = (u + 0x7FFFu + ((u >> 16) & 1u)) >> 16;
  return (unsigned short)r;
}
__device__ __forceinline__ float bf2f(unsigned short h) {
  return __uint_as_float(((unsigned int)h) << 16);
}
__device__ __forceinline__ float ldval(const float* p) { return *p; }
__device__ __forceinline__ float ldval(const unsigned short* p) { return bf2f(*p); }

// ---------------------------------------------------------------------------
// prep_kernel: fused [adjacency-list build | W1 transpose-split | W2 t-split].
// Block ranges: [0,2048) adj rows; [2048,2080) W1 tiles; [2080,2084) W2 tiles.
// ---------------------------------------------------------------------------
__global__ __launch_bounds__(256) void prep_kernel(
    const float* __restrict__ adj, int* __restrict__ nbr, int* __restrict__ deg,
    const float* __restrict__ W1, unsigned short* __restrict__ wt1h,
    unsigned short* __restrict__ wt1l, const float* __restrict__ W2,
    unsigned short* __restrict__ wt2h, unsigned short* __restrict__ wt2l) {
  __shared__ float ts[64][65];
  __shared__ int cnt;
  int bid = blockIdx.x;
  int tid = threadIdx.x;
  if (bid < N_) {
    int n = bid;
    if (tid == 0) cnt = 0;
    __syncthreads();
    for (int m = tid; m < N_; m += 256) {
      bool nz = adj[(size_t)n * N_ + m] != 0.0f;
      unsigned long long mask = __ballot(nz);
      int lane = tid & 63;
      int num = __popcll(mask);
      if (num) {               // wave-uniform
        int base = 0;
        if (lane == 0) base = atomicAdd(&cnt, num);
        base = __shfl(base, 0);
        if (nz) {
          int pos = base + __popcll(mask & ((1ull << lane) - 1ull));
          if (pos < MAXDEG) nbr[n * MAXDEG + pos] = m;
        }
      }
    }
    __syncthreads();
    if (tid == 0) deg[n] = cnt < MAXDEG ? cnt : MAXDEG;
  } else {
    int wk = bid - N_;
    const float* W;
    unsigned short *wth, *wtl;
    int KK, h, k0;
    if (wk < 32) { W = W1; wth = wt1h; wtl = wt1l; KK = 512; h = wk >> 3; k0 = (wk & 7) * 64; }
    else { wk -= 32; W = W2; wth = wt2h; wtl = wt2l; KK = 256; h = 0; k0 = wk * 64; }
    int kr = tid >> 2, nc = (tid & 3) * 16;
    const float* src = W + ((size_t)h * KK + k0 + kr) * 64 + nc;
#pragma unroll
    for (int j = 0; j < 4; ++j)
      *(float4*)&ts[kr][nc + 4 * j] = *(const float4*)(src + 4 * j);
    __syncthreads();
    int n = tid >> 2, kc = (tid & 3) * 16;
    short8 h0, h1v, l0, l1v;
#pragma unroll
    for (int j = 0; j < 8; ++j) {
      float a = ts[kc + j][n];
      float b = ts[kc + 8 + j][n];
      unsigned short ah = f2bf_rne(a), bh = f2bf_rne(b);
      h0[j] = (short)ah; h1v[j] = (short)bh;
      l0[j] = (short)f2bf_rne(a - bf2f(ah));
      l1v[j] = (short)f2bf_rne(b - bf2f(bh));
    }
    size_t o = ((size_t)h * 64 + n) * KK + k0 + kc;
    *(short8*)&wth[o]     = h0;
    *(short8*)&wth[o + 8] = h1v;
    *(short8*)&wtl[o]     = l0;
    *(short8*)&wtl[o + 8] = l1v;
  }
}

// ---------------------------------------------------------------------------
// Split-bf16 MFMA GEMM + fused rowdot, 32-ROW tiles (2x grid vs 64-row).
// 256 thr = 4 waves; wave w: rows (w&1)*16..+15, col-half (w>>1) (2 quadrants).
// MODE 0: X fp32 split in staging; grid 1024 = 256 rowtiles x 4 heads;
//   Yh bf16 [b,n,head*64+d]; rowdot vs a1[head].
// MODE 1: X pre-split hi/lo; grid 256; Yf fp32 [row,64]; rowdot vs a2.
// Per-element accumulation order identical to 64-tile version -> same bits.
// ---------------------------------------------------------------------------
template <int K, int MODE>
__global__ __launch_bounds__(256) void gemm_mfma_kernel(
    const float* __restrict__ Xf, const unsigned short* __restrict__ Xh,
    const unsigned short* __restrict__ Xl, const unsigned short* __restrict__ Wth,
    const unsigned short* __restrict__ Wtl, const float* __restrict__ avec,
    unsigned short* __restrict__ Yh, float* __restrict__ Yf,
    float* __restrict__ so_src, float* __restrict__ so_dst) {
  __shared__ unsigned short xsh[32][72], xsl[32][72], wsh[64][72], wsl[64][72];
  __shared__ float sd1[2][32], sd2[2][32];
  int tid = threadIdx.x;
  int w = tid >> 6, l = tid & 63;
  int wi = blockIdx.x;
  int head, row0;
  if (MODE == 0) { head = wi >> 8; row0 = (wi & 255) * 32; }
  else           { head = 0;       row0 = wi * 32; }
  int ch = w >> 1;              // col-half 0..1 (quadrants 2ch, 2ch+1)
  int rw = (w & 1) * 16;        // row base within tile
  const unsigned short* wh = Wth + (size_t)head * 64 * K;
  const unsigned short* wl = Wtl + (size_t)head * 64 * K;
  const float* av = avec + head * 128;

  int sxr = tid >> 3, sxc = (tid & 7) * 8;   // X staging: 32x64, 8/thread
  int swr = tid >> 2, swc = (tid & 3) * 16;  // W staging: 64x64, 16/thread

  f32x4 acc[2];
  acc[0] = (f32x4){0.f, 0.f, 0.f, 0.f};
  acc[1] = (f32x4){0.f, 0.f, 0.f, 0.f};

  for (int k0 = 0; k0 < K; k0 += 64) {
    if (MODE == 0) {
      const float* s0 = Xf + (size_t)(row0 + sxr) * K + k0 + sxc;
      float4 f0 = ((const float4*)s0)[0];
      float4 f1 = ((const float4*)s0)[1];
      float v[8] = {f0.x, f0.y, f0.z, f0.w, f1.x, f1.y, f1.z, f1.w};
      short8 hi, lo;
#pragma unroll
      for (int j = 0; j < 8; ++j) {
        unsigned short hh = f2bf_rne(v[j]);
        hi[j] = (short)hh;
        lo[j] = (short)f2bf_rne(v[j] - bf2f(hh));
      }
      *(short8*)&xsh[sxr][sxc] = hi;
      *(short8*)&xsl[sxr][sxc] = lo;
    } else {
      *(short8*)&xsh[sxr][sxc] =
          *(const short8*)(Xh + (size_t)(row0 + sxr) * K + k0 + sxc);
      *(short8*)&xsl[sxr][sxc] =
          *(const short8*)(Xl + (size_t)(row0 + sxr) * K + k0 + sxc);
    }
    {
      const unsigned short* s2 = wh + (size_t)swr * K + k0 + swc;
      const unsigned short* s3 = wl + (size_t)swr * K + k0 + swc;
      *(short8*)&wsh[swr][swc]     = *(const short8*)s2;
      *(short8*)&wsh[swr][swc + 8] = *(const short8*)(s2 + 8);
      *(short8*)&wsl[swr][swc]     = *(const short8*)s3;
      *(short8*)&wsl[swr][swc + 8] = *(const short8*)(s3 + 8);
    }
    __syncthreads();
#pragma unroll
    for (int ks = 0; ks < 2; ++ks) {
      int ko = ks * 32 + (l >> 4) * 8;
      int ar = rw + (l & 15);
      short8 ah = *(const short8*)&xsh[ar][ko];
      short8 al = *(const short8*)&xsl[ar][ko];
#pragma unroll
      for (int t = 0; t < 2; ++t) {
        int br = 16 * (2 * ch + t) + (l & 15);
        short8 bh = *(const short8*)&wsh[br][ko];
        short8 bl = *(const short8*)&wsl[br][ko];
        acc[t] = __builtin_amdgcn_mfma_f32_16x16x32_bf16(ah, bh, acc[t], 0, 0, 0);
        acc[t] = __builtin_amdgcn_mfma_f32_16x16x32_bf16(ah, bl, acc[t], 0, 0, 0);
        acc[t] = __builtin_amdgcn_mfma_f32_16x16x32_bf16(al, bh, acc[t], 0, 0, 0);
      }
    }
    __syncthreads();
  }

  int col = (l & 15);
  // ---- write Y ----
#pragma unroll
  for (int t = 0; t < 2; ++t) {
    int nt = 2 * ch + t;
#pragma unroll
    for (int j = 0; j < 4; ++j) {
      int r = rw + (l >> 4) * 4 + j;
      size_t gr = row0 + r;
      if (MODE == 0)
        Yh[gr * (NHEADS * 64) + head * 64 + 16 * nt + col] = f2bf_rne(acc[t][j]);
      else
        Yf[gr * 64 + 16 * nt + col] = acc[t][j];
    }
  }
  // ---- fused rowdot: partial over this wave's 2 quadrants ----
  float aS[2], aD[2];
#pragma unroll
  for (int t = 0; t < 2; ++t) {
    int nt = 2 * ch + t;
    aS[t] = av[16 * nt + col];
    aD[t] = av[64 + 16 * nt + col];
  }
  float s1[4] = {0.f, 0.f, 0.f, 0.f}, s2[4] = {0.f, 0.f, 0.f, 0.f};
#pragma unroll
  for (int t = 0; t < 2; ++t)
#pragma unroll
    for (int j = 0; j < 4; ++j) {
      s1[j] = fmaf(acc[t][j], aS[t], s1[j]);
      s2[j] = fmaf(acc[t][j], aD[t], s2[j]);
    }
#pragma unroll
  for (int off = 1; off < 16; off <<= 1) {
#pragma unroll
    for (int j = 0; j < 4; ++j) {
      s1[j] += __shfl_xor(s1[j], off);
      s2[j] += __shfl_xor(s2[j], off);
    }
  }
  if (col == 0) {
#pragma unroll
    for (int j = 0; j < 4; ++j) {
      int r = rw + (l >> 4) * 4 + j;
      sd1[ch][r] = s1[j];
      sd2[ch][r] = s2[j];
    }
  }
  __syncthreads();
  if (tid < 32) {
    int gr = row0 + tid;
    float t1 = sd1[0][tid] + sd1[1][tid];
    float t2 = sd2[0][tid] + sd2[1][tid];
    size_t si;
    if (MODE == 0) {
      int b = gr >> 11, n = gr & (N_ - 1);
      si = (size_t)(b * NHEADS + head) * N_ + n;
    } else {
      si = gr;
    }
    so_src[si] = t1;
    so_dst[si] = t2;
  }
}

// ---------------------------------------------------------------------------
// Sparse attention aggregation: 16-deep then 8-deep software pipeline.
// ---------------------------------------------------------------------------
template <int RS, typename T>
__device__ __forceinline__ float sparse_agg(
    const T* __restrict__ plane, const float* __restrict__ sdb,
    const int* __restrict__ nb, int dg, float ss, int lane) {
  float acc0 = 0.f, acc1 = 0.f, acc2 = 0.f, acc3 = 0.f;
  float den0 = 0.f, den1 = 0.f, den2 = 0.f, den3 = 0.f;
  int k = 0;
  for (; k + 16 <= dg; k += 16) {
    int m[16];
    float sv[16], hv[16];
#pragma unroll
    for (int j = 0; j < 16; ++j) m[j] = nb[k + j];
#pragma unroll
    for (int j = 0; j < 16; ++j) sv[j] = sdb[m[j]];
#pragma unroll
    for (int j = 0; j < 16; ++j) hv[j] = ldval(&plane[(size_t)m[j] * RS + lane]);
#pragma unroll
    for (int j = 0; j < 16; ++j) {
      float s = ss + sv[j];
      float lr = s > 0.f ? s : LRELU_ALPHA * s;
      float ev = __expf(-lr);
      switch (j & 3) {
        case 0: den0 += ev; acc0 = fmaf(ev, hv[j], acc0); break;
        case 1: den1 += ev; acc1 = fmaf(ev, hv[j], acc1); break;
        case 2: den2 += ev; acc2 = fmaf(ev, hv[j], acc2); break;
        default: den3 += ev; acc3 = fmaf(ev, hv[j], acc3); break;
      }
    }
  }
  for (; k + 8 <= dg; k += 8) {
    int m[8];
    float sv[8], hv[8];
#pragma unroll
    for (int j = 0; j < 8; ++j) m[j] = nb[k + j];
#pragma unroll
    for (int j = 0; j < 8; ++j) sv[j] = sdb[m[j]];
#pragma unroll
    for (int j = 0; j < 8; ++j) hv[j] = ldval(&plane[(size_t)m[j] * RS + lane]);
#pragma unroll
    for (int j = 0; j < 8; ++j) {
      float s = ss + sv[j];
      float lr = s > 0.f ? s : LRELU_ALPHA * s;
      float ev = __expf(-lr);
      if (j & 1) { den1 += ev; acc1 = fmaf(ev, hv[j], acc1); }
      else       { den0 += ev; acc0 = fmaf(ev, hv[j], acc0); }
    }
  }
  for (; k < dg; ++k) {
    int m = nb[k];
    float s = ss + sdb[m];
    float lr = s > 0.f ? s : LRELU_ALPHA * s;
    float ev = __expf(-lr);
    den0 += ev;
    acc0 = fmaf(ev, ldval(&plane[(size_t)m * RS + lane]), acc0);
  }
  return ((acc0 + acc1) + (acc2 + acc3)) / ((den0 + den1) + (den2 + den3));
}

// ---------------------------------------------------------------------------
// Layer-1 aggregation: one BLOCK per (b,n); 4 waves = 4 heads. h is BF16.
// ---------------------------------------------------------------------------
__global__ __launch_bounds__(256) void attn1_kernel(
    const unsigned short* __restrict__ Hm, const float* __restrict__ ssrc,
    const float* __restrict__ sdst, const int* __restrict__ nbr,
    const int* __restrict__ deg, unsigned short* __restrict__ h1h,
    unsigned short* __restrict__ h1l) {
  int bn = blockIdx.x;               // 0..B*N-1
  int n = bn & (N_ - 1), b = bn >> 11;
  int w = threadIdx.x >> 6;          // head
  int lane = threadIdx.x & 63;
  __shared__ int lds_nbr[MAXDEG];
  int dg = deg[n];
  for (int k = threadIdx.x; k < dg; k += 256) lds_nbr[k] = nbr[n * MAXDEG + k];
  __syncthreads();
  int bh = b * NHEADS + w;
  float ss = ssrc[(size_t)bh * N_ + n];
  const float* sdb = sdst + (size_t)bh * N_;
  const unsigned short* plane = Hm + (size_t)b * N_ * (NHEADS * 64) + w * 64;
  float o = sparse_agg<NHEADS * 64>(plane, sdb, lds_nbr, dg, ss, lane);
  o = o > 0.f ? o : expm1f(o);
  unsigned short hi = f2bf_rne(o);
  size_t oi = (size_t)bn * (NHEADS * NHID) + w * 64 + lane;
  h1h[oi] = hi;
  h1l[oi] = f2bf_rne(o - bf2f(hi));
}

// ---------------------------------------------------------------------------
// Layer-2 aggregation + final ELU -> d_out. One wave per (b,n). g stays fp32.
// ---------------------------------------------------------------------------
__global__ __launch_bounds__(256) void attn2_kernel(
    const float* __restrict__ G, const float* __restrict__ tsrc,
    const float* __restrict__ tdst, const int* __restrict__ nbr,
    const int* __restrict__ deg, float* __restrict__ out) {
  int w = threadIdx.x >> 6, lane = threadIdx.x & 63;
  int gr = blockIdx.x * 4 + w;        // 0..B*N
  int n = gr & (N_ - 1);
  int b = gr >> 11;
  float o = sparse_agg<64>(G + (size_t)b * N_ * 64, tdst + (size_t)b * N_,
                           nbr + n * MAXDEG, deg[n], tsrc[gr], lane);
  out[(size_t)gr * 64 + lane] = o > 0.f ? o : expm1f(o);
}

// ---------------------------------------------------------------------------
extern "C" void kernel_launch(void* const* d_in, const int* in_sizes, int n_in,
                              void* d_out, int out_size, void* d_ws, size_t ws_size,
                              hipStream_t stream) {
  const float* x   = (const float*)d_in[0];   // [B,N,512]
  const float* adj = (const float*)d_in[1];   // [N,N]
  const float* W1  = (const float*)d_in[2];   // [H,512,64]
  const float* a1  = (const float*)d_in[3];   // [H,128]
  const float* W2  = (const float*)d_in[4];   // [256,64]
  const float* a2  = (const float*)d_in[5];   // [128]
  float* out = (float*)d_out;                 // [B,N,64] fp32

  char* ws = (char*)d_ws;
  unsigned short* h = (unsigned short*)ws; ws += (size_t)B_ * N_ * 256 * 2;  // 4.2 MB bf16
  float* g    = (float*)ws; ws += (size_t)B_ * N_ * 64 * 4;           // 2 MB
  float* ssrc = (float*)ws; ws += (size_t)B_ * NHEADS * N_ * 4;
  float* sdst = (float*)ws; ws += (size_t)B_ * NHEADS * N_ * 4;
  float* tsrc = (float*)ws; ws += (size_t)B_ * N_ * 4;
  float* tdst = (float*)ws; ws += (size_t)B_ * N_ * 4;
  int*   nbr  = (int*)ws;   ws += (size_t)N_ * MAXDEG * 4;            // 1 MB
  int*   deg  = (int*)ws;   ws += (size_t)N_ * 4;
  ws = (char*)(((size_t)ws + 255) & ~(size_t)255);
  unsigned short* wt1h = (unsigned short*)ws; ws += (size_t)NHEADS * 64 * NFEAT * 2;
  unsigned short* wt1l = (unsigned short*)ws; ws += (size_t)NHEADS * 64 * NFEAT * 2;
  unsigned short* wt2h = (unsigned short*)ws; ws += (size_t)64 * 256 * 2;
  unsigned short* wt2l = (unsigned short*)ws; ws += (size_t)64 * 256 * 2;
  unsigned short* h1h  = (unsigned short*)ws; ws += (size_t)B_ * N_ * 256 * 2;   // 4.2 MB
  unsigned short* h1l  = (unsigned short*)ws; ws += (size_t)B_ * N_ * 256 * 2;   // 4.2 MB

  // prep: blocks [0,2048) adj | [2048,2080) W1 | [2080,2084) W2
  prep_kernel<<<N_ + 32 + 4, 256, 0, stream>>>(adj, nbr, deg, W1, wt1h, wt1l,
                                               W2, wt2h, wt2l);
  // gemm1: 256 rowtiles x 4 heads (32-row tiles)
  gemm_mfma_kernel<NFEAT, 0><<<(B_ * N_ / 32) * NHEADS, 256, 0, stream>>>(
      x, nullptr, nullptr, wt1h, wt1l, a1, h, nullptr, ssrc, sdst);
  attn1_kernel<<<B_ * N_, 256, 0, stream>>>(h, ssrc, sdst, nbr, deg, h1h, h1l);
  // gemm2: 256 rowtiles (32-row tiles) -> every CU gets a block
  gemm_mfma_kernel<256, 1><<<B_ * N_ / 32, 256, 0, stream>>>(
      nullptr, h1h, h1l, wt2h, wt2l, a2, nullptr, g, tsrc, tdst);
  attn2_kernel<<<B_ * N_ / 4, 256, 0, stream>>>(g, tsrc, tdst, nbr, deg, out);
}